// Round 3
// baseline (33.660 us; speedup 1.0000x reference)
//
#include <hip/hip_runtime.h>

static constexpr float INV_SQRT2 = 0.70710678118654752f;
static constexpr float INV_SQRT3 = 0.57735026918962576f;
static constexpr float SQRT2     = 1.41421356237309505f;
static constexpr float INV_SQRT6 = 0.40824829046386302f;

// Each wave (64 lanes) owns 512 contiguous nodes = 8 chunks of 64.
// batch is sorted, so segments are contiguous runs -> shuffle-based
// segmented inclusive scan + cross-chunk carry; ~2 atomics per segment.
__global__ __launch_bounds__(256) void e3nn_main(
    const int*   __restrict__ z,
    const float* __restrict__ pos,
    const int*   __restrict__ batch,
    const float* __restrict__ w_tp,
    const float* __restrict__ fc_w,
    const float* __restrict__ fc_b,
    float* __restrict__ sums,
    float* __restrict__ cnts,
    int n)
{
    const int lane  = threadIdx.x & 63;
    const int gwave = (blockIdx.x * blockDim.x + threadIdx.x) >> 6;
    const int base  = gwave * 512;
    if (base >= n) return;

    // uniform weights (compile-time indices -> scalar loads)
    const float wA0 = w_tp[0], wA1 = w_tp[1];
    const float wB0 = w_tp[2], wB1 = w_tp[3];
    const float c0  = (w_tp[4] + w_tp[6]) * INV_SQRT2;
    const float c1  = (w_tp[5] + w_tp[7]) * INV_SQRT2;
    const float wE  = w_tp[8];
    float fw[13];
#pragma unroll
    for (int j = 0; j < 13; ++j) fw[j] = fc_w[j];
    const float fb = fc_b[0];

    int   carry_b   = -1;
    float carry_sum = 0.f;
    float carry_cnt = 0.f;

#pragma unroll 1
    for (int c = 0; c < 8; ++c) {
        const int i = base + c * 64 + lane;
        int   b = -1;
        float y = 0.f;
        float valid = 0.f;
        if (i < n) {
            b = batch[i];
            valid = 1.f;
            const float s  = (float)z[i];
            const float v0 = pos[i * 3 + 0];
            const float v1 = pos[i * 3 + 1];
            const float v2 = pos[i * 3 + 2];

            const float ss   = s * s;
            const float dot3 = (v0 * v0 + v1 * v1 + v2 * v2) * INV_SQRT3;

            float x0 = (ss * wA0 + dot3 * wB0) * INV_SQRT2;
            float x1 = (ss * wA1 + dot3 * wB1) * INV_SQRT2;

            const float sv0 = s * v0, sv1 = s * v1, sv2 = s * v2;
            float x2 = sv0 * c0, x3 = sv1 * c0, x4 = sv2 * c0;
            float x5 = sv0 * c1, x6 = sv1 * c1, x7 = sv2 * c1;

            float x8  = wE * (SQRT2 * v0 * v1);
            float x9  = wE * (SQRT2 * v1 * v2);
            float x10 = wE * (SQRT2 * v0 * v2);
            float x11 = wE * (INV_SQRT2 * (v0 * v0 - v1 * v1));
            float x12 = wE * (INV_SQRT6 * (2.f * v2 * v2 - v0 * v0 - v1 * v1));

            float acc = fb;
            acc += fmaxf(x0, 0.f) * fw[0];
            acc += fmaxf(x1, 0.f) * fw[1];
            acc += fmaxf(x2, 0.f) * fw[2];
            acc += fmaxf(x3, 0.f) * fw[3];
            acc += fmaxf(x4, 0.f) * fw[4];
            acc += fmaxf(x5, 0.f) * fw[5];
            acc += fmaxf(x6, 0.f) * fw[6];
            acc += fmaxf(x7, 0.f) * fw[7];
            acc += fmaxf(x8, 0.f) * fw[8];
            acc += fmaxf(x9, 0.f) * fw[9];
            acc += fmaxf(x10, 0.f) * fw[10];
            acc += fmaxf(x11, 0.f) * fw[11];
            acc += fmaxf(x12, 0.f) * fw[12];
            y = tanhf(acc);
        }

        // If the pending carry's graph ended at the previous chunk boundary,
        // flush it (uniform condition across the wave).
        const int b0 = __shfl(b, 0);
        if (carry_b >= 0 && carry_b != b0) {
            if (lane == 0) {
                atomicAdd(&sums[carry_b], carry_sum);
                atomicAdd(&cnts[carry_b], carry_cnt);
            }
            carry_b = -1; carry_sum = 0.f; carry_cnt = 0.f;
        }

        // Segmented inclusive scan (keys are contiguous runs -> the simple
        // "add neighbor if same key" Hillis-Steele variant is exact).
        float sum = y;
        float cnt = valid;
#pragma unroll
        for (int off = 1; off < 64; off <<= 1) {
            const float s_up = __shfl_up(sum, off);
            const float n_up = __shfl_up(cnt, off);
            const int   b_up = __shfl_up(b, off);
            if (lane >= off && b_up == b) { sum += s_up; cnt += n_up; }
        }

        // Merge carry into the first segment (b == carry_b implies first run).
        float eff_sum = sum, eff_cnt = cnt;
        if (b == carry_b) { eff_sum += carry_sum; eff_cnt += carry_cnt; }

        // Segment tails flush; lane 63's segment becomes the new carry.
        const int b_dn = __shfl_down(b, 1);
        const bool tail = (b_dn != b);
        if (tail && lane != 63 && b >= 0) {
            atomicAdd(&sums[b], eff_sum);
            atomicAdd(&cnts[b], eff_cnt);
        }
        carry_b   = __shfl(b, 63);
        carry_sum = __shfl(eff_sum, 63);
        carry_cnt = __shfl(eff_cnt, 63);
    }

    if (lane == 0 && carry_b >= 0) {
        atomicAdd(&sums[carry_b], carry_sum);
        atomicAdd(&cnts[carry_b], carry_cnt);
    }
}

__global__ __launch_bounds__(256) void e3nn_finalize(
    const float* __restrict__ sums,
    const float* __restrict__ cnts,
    float* __restrict__ out,
    int n_graphs)
{
    const int g = blockIdx.x * blockDim.x + threadIdx.x;
    if (g < n_graphs) {
        out[g] = sums[g] / fmaxf(cnts[g], 1.0f);
    }
}

extern "C" void kernel_launch(void* const* d_in, const int* in_sizes, int n_in,
                              void* d_out, int out_size, void* d_ws, size_t ws_size,
                              hipStream_t stream) {
    const int*   z     = (const int*)d_in[0];
    const float* pos   = (const float*)d_in[1];
    const int*   batch = (const int*)d_in[2];
    const float* w_tp  = (const float*)d_in[3];
    const float* fc_w  = (const float*)d_in[4];
    const float* fc_b  = (const float*)d_in[5];

    float* out  = (float*)d_out;
    float* sums = (float*)d_ws;
    const int n        = in_sizes[0];
    const int n_graphs = out_size;
    float* cnts = sums + n_graphs;

    hipMemsetAsync(d_ws, 0, (size_t)2 * n_graphs * sizeof(float), stream);

    const int total_waves   = (n + 511) / 512;
    const int total_threads = total_waves * 64;
    const int blocks        = (total_threads + 255) / 256;
    e3nn_main<<<blocks, 256, 0, stream>>>(z, pos, batch, w_tp, fc_w, fc_b,
                                          sums, cnts, n);

    const int fblocks = (n_graphs + 255) / 256;
    e3nn_finalize<<<fblocks, 256, 0, stream>>>(sums, cnts, out, n_graphs);
}